// Round 7
// baseline (287.948 us; speedup 1.0000x reference)
//
#include <hip/hip_runtime.h>

// B=2, N=2048, D=1024, H=16, HS=64.
#define D_MODEL 1024
#define NSEQ    2048
#define NBATCH  2
#define NHEAD   16
#define HSZ     64
#define MROWS   4096   // B*N

typedef short s8v  __attribute__((ext_vector_type(8)));   // 8 x bf16 (bit-pattern shorts)
typedef float f32x4 __attribute__((ext_vector_type(4)));

#define AS1(p) ((__attribute__((address_space(1))) const void*)(p))
#define AS3(p) ((__attribute__((address_space(3))) void*)(p))

__device__ __forceinline__ float b2f(unsigned short s) {
    union { unsigned u; float f; } z; z.u = (unsigned)s << 16; return z.f;
}
__device__ __forceinline__ unsigned short f2b(float f) {
    union { float f; unsigned u; } z; z.f = f;
    unsigned r = z.u + 0x7fffu + ((z.u >> 16) & 1u);   // RNE
    return (unsigned short)(r >> 16);
}
__device__ __forceinline__ unsigned short f2b_trunc(float f) {
    union { float f; unsigned u; } z; z.f = f;
    return (unsigned short)(z.u >> 16);
}
__device__ __forceinline__ float gelu_f(float x) {
    float u = 0.7978845608028654f * (x + 0.044715f * x * x * x);
    float t = 1.f - 2.f / (1.f + __expf(2.f * u));     // tanh(u), saturating
    return 0.5f * x * (1.f + t);
}

// ---------- dtype sniff ----------
__global__ __launch_bounds__(256) void sniff_k(const unsigned short* __restrict__ xr,
                                               int* __restrict__ flag) {
    __shared__ int cnt[4];
    int tid = threadIdx.x, ok = 0;
    for (int i = tid; i < 2048; i += 256) {
        unsigned short u = xr[i];
        int e = (u >> 7) & 0xFF;
        if (u == 0 || (e >= 110 && e <= 135)) ok++;
    }
    #pragma unroll
    for (int off = 32; off; off >>= 1) ok += __shfl_down(ok, off);
    if ((tid & 63) == 0) cnt[tid >> 6] = ok;
    __syncthreads();
    if (tid == 0) {
        int tot = cnt[0] + cnt[1] + cnt[2] + cnt[3];
        *flag = (tot > 1843) ? 1 : 0;
    }
}

// ---------- all 7 small vectors in one launch ----------
__global__ __launch_bounds__(256) void cvt_small_k(
    const void* p0, const void* p1, const void* p2, const void* p3,
    const void* p4, const void* p5, const void* p6,
    unsigned short* __restrict__ out, const int* __restrict__ flag)
{
    int i = blockIdx.x * 256 + threadIdx.x;   // 0..8191
    const void* src; int off;
    if      (i < 1024) { src = p0; off = i; }
    else if (i < 2048) { src = p1; off = i - 1024; }
    else if (i < 3072) { src = p2; off = i - 2048; }
    else if (i < 4096) { src = p3; off = i - 3072; }
    else if (i < 5120) { src = p4; off = i - 4096; }
    else if (i < 7168) { src = p5; off = i - 5120; }
    else               { src = p6; off = i - 7168; }
    out[i] = (*flag) ? ((const unsigned short*)src)[off]
                     : f2b(((const float*)src)[off]);
}

// ---------- all 4 weight transposes in one launch ----------
__global__ __launch_bounds__(256) void transpose_all_k(
    const void* wqkv, const void* wout, const void* w1, const void* w2,
    unsigned short* t_qkv, unsigned short* t_out,
    unsigned short* t_w1, unsigned short* t_w2, const int* __restrict__ flag)
{
    __shared__ unsigned short t[32][33];
    int bid = blockIdx.x;
    const void* W; unsigned short* Wt; int K, N, bx, by;
    if      (bid < 3072) { W = wqkv; Wt = t_qkv; K = 1024; N = 3072; bx = bid % 96; by = bid / 96; }
    else if (bid < 4096) { bid -= 3072; W = wout; Wt = t_out; K = 1024; N = 1024; bx = bid % 32; by = bid / 32; }
    else if (bid < 6144) { bid -= 4096; W = w1;   Wt = t_w1;  K = 1024; N = 2048; bx = bid % 64; by = bid / 64; }
    else                 { bid -= 6144; W = w2;   Wt = t_w2;  K = 2048; N = 1024; bx = bid % 32; by = bid / 32; }
    int f = *flag;
    int n0 = bx * 32, k0 = by * 32;
    int x = threadIdx.x & 31, y = threadIdx.x >> 5;   // (32,8) flat
    #pragma unroll
    for (int r = 0; r < 32; r += 8) {
        size_t idx = (size_t)(k0 + r + y) * N + n0 + x;
        t[r + y][x] = f ? ((const unsigned short*)W)[idx]
                        : f2b(((const float*)W)[idx]);
    }
    __syncthreads();
    #pragma unroll
    for (int r = 0; r < 32; r += 8)
        Wt[(size_t)(n0 + r + y) * K + k0 + x] = t[x][r + y];
}

// ---------- LN1 fused with x canonicalization ----------
__global__ __launch_bounds__(256) void ln1f_k(
    const void* __restrict__ x_raw, const unsigned short* __restrict__ scale,
    const unsigned short* __restrict__ bias, unsigned short* __restrict__ xb,
    unsigned short* __restrict__ xn, const int* __restrict__ flag)
{
    int row = blockIdx.x, tid = threadIdx.x;
    int f = *flag;
    float v[4], s = 0.f, s2 = 0.f;
    #pragma unroll
    for (int i = 0; i < 4; ++i) {
        size_t idx = (size_t)row * D_MODEL + tid + i * 256;
        float t = f ? b2f(((const unsigned short*)x_raw)[idx])
                    : ((const float*)x_raw)[idx];
        v[i] = t; s += t; s2 += t * t;
    }
    #pragma unroll
    for (int off = 32; off; off >>= 1) { s += __shfl_down(s, off); s2 += __shfl_down(s2, off); }
    __shared__ float rs[4], rs2[4];
    int w = tid >> 6;
    if ((tid & 63) == 0) { rs[w] = s; rs2[w] = s2; }
    __syncthreads();
    float S  = rs[0] + rs[1] + rs[2] + rs[3];
    float S2 = rs2[0] + rs2[1] + rs2[2] + rs2[3];
    float mean = S * (1.f / D_MODEL);
    float var  = S2 * (1.f / D_MODEL) - mean * mean;
    float rstd = rsqrtf(var + 1e-6f);
    #pragma unroll
    for (int i = 0; i < 4; ++i) {
        int d = tid + i * 256;
        size_t idx = (size_t)row * D_MODEL + d;
        xb[idx] = f2b(v[i]);
        xn[idx] = f2b((v[i] - mean) * rstd * b2f(scale[d]) + b2f(bias[d]));
    }
}

// ---------- LayerNorm (bf16 in) ----------
__global__ __launch_bounds__(256) void ln_k(
    const unsigned short* __restrict__ x, const unsigned short* __restrict__ scale,
    const unsigned short* __restrict__ bias, unsigned short* __restrict__ out)
{
    int row = blockIdx.x, tid = threadIdx.x;
    const unsigned short* xr = x + (size_t)row * D_MODEL;
    float v[4], s = 0.f, s2 = 0.f;
    #pragma unroll
    for (int i = 0; i < 4; ++i) {
        float t = b2f(xr[tid + i * 256]);
        v[i] = t; s += t; s2 += t * t;
    }
    #pragma unroll
    for (int off = 32; off; off >>= 1) { s += __shfl_down(s, off); s2 += __shfl_down(s2, off); }
    __shared__ float rs[4], rs2[4];
    int w = tid >> 6;
    if ((tid & 63) == 0) { rs[w] = s; rs2[w] = s2; }
    __syncthreads();
    float S  = rs[0] + rs[1] + rs[2] + rs[3];
    float S2 = rs2[0] + rs2[1] + rs2[2] + rs2[3];
    float mean = S * (1.f / D_MODEL);
    float var  = S2 * (1.f / D_MODEL) - mean * mean;
    float rstd = rsqrtf(var + 1e-6f);
    #pragma unroll
    for (int i = 0; i < 4; ++i) {
        int d = tid + i * 256;
        out[(size_t)row * D_MODEL + d] =
            f2b((v[i] - mean) * rstd * b2f(scale[d]) + b2f(bias[d]));
    }
}

// ---------- GEMM: 128xTN tile, BK=64, global_load_lds, coalesced LDS epilogue ----------
template<int TN, int ACT, int RES, int ODYN>
__global__ __launch_bounds__(256) void gemm128_k(
    const unsigned short* __restrict__ A, const unsigned short* __restrict__ Bt,
    const unsigned short* __restrict__ bias, const unsigned short* __restrict__ resid,
    void* __restrict__ Cp, int M, int Nn, int K, const int* __restrict__ flag)
{
    constexpr int MT = (TN == 128) ? 4 : 2;
    constexpr int SW = TN + 4;                       // epilogue tile stride (shorts)
    constexpr int STAGE = 128 * 64 + TN * 64;        // K-loop staging shorts
    constexpr int EPI   = 128 * SW;                  // epilogue tile shorts
    constexpr int SMEMN = (STAGE > EPI) ? STAGE : EPI;
    __shared__ short smem[SMEMN];
    short* As = smem;
    short* Bs = smem + 128 * 64;
    int tid = threadIdx.x;
    int m0 = blockIdx.y * 128, n0 = blockIdx.x * TN;
    int lane = tid & 63, w = tid >> 6;
    int a_base = (TN == 128) ? (w >> 1) * 64 : w * 32;
    int b_base = (TN == 128) ? (w & 1) * 64 : 0;
    int mm = lane & 15, q = lane >> 4;

    f32x4 zero = {0.f, 0.f, 0.f, 0.f};
    f32x4 acc[MT][4];
    #pragma unroll
    for (int mt = 0; mt < MT; ++mt)
        #pragma unroll
        for (int nt = 0; nt < 4; ++nt) acc[mt][nt] = zero;

    int grow   = lane >> 3;
    int gchunk = ((lane & 7) ^ grow) * 8;
    const unsigned short* Ab = A  + (size_t)(m0 + w * 32 + grow) * K + gchunk;
    const unsigned short* Bb = Bt + (size_t)(n0 + w * (TN / 4) + grow) * K + gchunk;
    int swz = (mm & 7);

    for (int k0 = 0; k0 < K; k0 += 64) {
        __syncthreads();
        #pragma unroll
        for (int s = 0; s < 4; ++s)
            __builtin_amdgcn_global_load_lds(AS1(Ab + k0 + (size_t)(s * 8) * K),
                                             AS3(&As[(w * 32 + s * 8) * 64]), 16, 0, 0);
        #pragma unroll
        for (int s = 0; s < TN / 32; ++s)
            __builtin_amdgcn_global_load_lds(AS1(Bb + k0 + (size_t)(s * 8) * K),
                                             AS3(&Bs[(w * (TN / 4) + s * 8) * 64]), 16, 0, 0);
        __syncthreads();
        #pragma unroll
        for (int kk = 0; kk < 2; ++kk) {
            int col = ((kk * 4 + q) ^ swz) * 8;
            s8v af[MT], bf[4];
            #pragma unroll
            for (int mt = 0; mt < MT; ++mt)
                af[mt] = *(const s8v*)&As[(a_base + mt * 16 + mm) * 64 + col];
            #pragma unroll
            for (int nt = 0; nt < 4; ++nt)
                bf[nt] = *(const s8v*)&Bs[(b_base + nt * 16 + mm) * 64 + col];
            #pragma unroll
            for (int mt = 0; mt < MT; ++mt)
                #pragma unroll
                for (int nt = 0; nt < 4; ++nt)
                    acc[mt][nt] = __builtin_amdgcn_mfma_f32_16x16x32_bf16(
                        af[mt], bf[nt], acc[mt][nt], 0, 0, 0);
        }
    }

    // ---- epilogue: acc -> LDS (bf16) -> coalesced global stores ----
    __syncthreads();   // all waves done reading staged tiles
    #pragma unroll
    for (int nt = 0; nt < 4; ++nt)
        #pragma unroll
        for (int mt = 0; mt < MT; ++mt)
            #pragma unroll
            for (int r = 0; r < 4; ++r)
                smem[(a_base + mt * 16 + q * 4 + r) * SW + b_base + nt * 16 + mm] =
                    (short)f2b(acc[mt][nt][r]);
    __syncthreads();

    constexpr int LPR = TN / 8;        // lanes per row
    constexpr int RPP = 256 / LPR;     // rows per pass
    int erow = tid / LPR;
    int ecol = (tid % LPR) * 8;
    int f = ODYN ? *flag : 1;
    float bias8[8];
    #pragma unroll
    for (int e = 0; e < 8; ++e) bias8[e] = bias ? b2f(bias[n0 + ecol + e]) : 0.f;

    #pragma unroll
    for (int p = 0; p < 128 / RPP; ++p) {
        int row = p * RPP + erow;
        int gr = m0 + row;
        s8v vv = *(const s8v*)&smem[row * SW + ecol];
        float vf[8];
        #pragma unroll
        for (int e = 0; e < 8; ++e) {
            vf[e] = b2f((unsigned short)vv[e]) + bias8[e];
            if (ACT == 1) vf[e] = gelu_f(vf[e]);
        }
        if (RES == 1) {
            s8v rv = *(const s8v*)(resid + (size_t)gr * Nn + n0 + ecol);
            #pragma unroll
            for (int e = 0; e < 8; ++e) vf[e] += b2f((unsigned short)rv[e]);
        }
        if (f) {
            s8v ov;
            #pragma unroll
            for (int e = 0; e < 8; ++e) ov[e] = (short)f2b(vf[e]);
            *(s8v*)&((unsigned short*)Cp)[(size_t)gr * Nn + n0 + ecol] = ov;
        } else {
            f32x4 o0 = {vf[0], vf[1], vf[2], vf[3]};
            f32x4 o1 = {vf[4], vf[5], vf[6], vf[7]};
            *(f32x4*)&((float*)Cp)[(size_t)gr * Nn + n0 + ecol] = o0;
            *(f32x4*)&((float*)Cp)[(size_t)gr * Nn + n0 + ecol + 4] = o1;
        }
    }
}

// ---------- flash attention v4: no-max softmax, l via ones-MFMA, prescaled Q ----------
__global__ __launch_bounds__(256, 3) void fattn_k(
    const unsigned short* __restrict__ qkv, unsigned short* __restrict__ attn_out)
{
    int bh = blockIdx.x;
    int h = bh & (NHEAD - 1), b = bh >> 4;
    int qt = gridDim.y - 1 - blockIdx.y;          // heaviest first
    int q0 = qt * 64;
    size_t base = (size_t)b * NSEQ * (3 * D_MODEL);

    __shared__ __align__(16) short Ks[128][72];    // [key][dim]
    __shared__ __align__(16) short Vts[64][136];   // [dim][key pair-swizzled]
    __shared__ __align__(16) short Ps[64][136];    // [query][key, col+16*rowquad swizzle]

    int tid = threadIdx.x, lane = tid & 63, w = tid >> 6;
    int mm = lane & 15, q = lane >> 4;

    // Q fragments, pre-scaled by 1/sqrt(64)=0.125 (exact exponent shift in bf16)
    s8v qf[2];
    #pragma unroll
    for (int kk = 0; kk < 2; ++kk) {
        s8v t = *(const s8v*)(qkv + base + (size_t)(q0 + w * 16 + mm) * (3 * D_MODEL)
                              + h * HSZ + kk * 32 + q * 8);
        #pragma unroll
        for (int e = 0; e < 8; ++e)
            t[e] = (short)f2b_trunc(b2f((unsigned short)t[e]) * 0.125f);  // exact
        qf[kk] = t;
    }

    f32x4 zero = {0.f, 0.f, 0.f, 0.f};
    f32x4 acc_o[4] = {zero, zero, zero, zero};
    f32x4 acc_l = zero;
    const s8v ones = {0x3F80, 0x3F80, 0x3F80, 0x3F80, 0x3F80, 0x3F80, 0x3F80, 0x3F80};

    int kr = tid >> 1;            // K staging row 0..127
    int kc = (tid & 1) * 32;      // 0 or 32
    int kp = tid >> 3;            // V key-pair 0..31
    int vd = (tid & 7) * 8;       // V dim base

    const unsigned short* kbase = qkv + base + D_MODEL + h * HSZ;
    const unsigned short* vbase = qkv + base + 2 * D_MODEL + h * HSZ;

    int nstages = (qt + 2) >> 1;

    s8v kv0, kv1, kv2, kv3, vv0, vv1, vv2, vv3;
    {
        const unsigned short* kb = kbase;
        const unsigned short* vb = vbase;
        kv0 = *(const s8v*)(kb + (size_t)kr * (3 * D_MODEL) + kc);
        kv1 = *(const s8v*)(kb + (size_t)kr * (3 * D_MODEL) + kc + 8);
        kv2 = *(const s8v*)(kb + (size_t)kr * (3 * D_MODEL) + kc + 16);
        kv3 = *(const s8v*)(kb + (size_t)kr * (3 * D_MODEL) + kc + 24);
        vv0 = *(const s8v*)(vb + (size_t)(2 * kp)      * (3 * D_MODEL) + vd);
        vv1 = *(const s8v*)(vb + (size_t)(2 * kp + 1)  * (3 * D_MODEL) + vd);
        vv2 = *(const s8v*)(vb + (size_t)(2 * kp + 64) * (3 * D_MODEL) + vd);
        vv3 = *(const s8v*)(vb + (size_t)(2 * kp + 65) * (3 * D_MODEL) + vd);
    }

    for (int t = 0; t < nstages; ++t) {
        int j0 = t * 128;
        int nsub = (j0 < q0) ? 2 : 1;

        __syncthreads();
        *(s8v*)&Ks[kr][kc]      = kv0;
        *(s8v*)&Ks[kr][kc + 8]  = kv1;
        *(s8v*)&Ks[kr][kc + 16] = kv2;
        *(s8v*)&Ks[kr][kc + 24] = kv3;
        int c0 = (2 * kp + vd) & 63;
        #pragma unroll
        for (int e = 0; e < 8; ++e) {
            unsigned p0 = (unsigned)(unsigned short)vv0[e] |
                          ((unsigned)(unsigned short)vv1[e] << 16);
            unsigned p1 = (unsigned)(unsigned short)vv2[e] |
                          ((unsigned)(unsigned short)vv3[e] << 16);
            *(unsigned*)&Vts[vd + e][c0]      = p0;
            *(unsigned*)&Vts[vd + e][64 + c0] = p1;
        }
        if (t + 1 < nstages) {
            const unsigned short* kb = kbase + (size_t)(j0 + 128) * (3 * D_MODEL);
            const unsigned short* vb = vbase + (size_t)(j0 + 128) * (3 * D_MODEL);
            kv0 = *(const s8v*)(kb + (size_t)kr * (3 * D_MODEL) + kc);
            kv1 = *(const s8v*)(kb + (size_t)kr * (3 * D_MODEL) + kc + 8);
            kv2 = *(const s8v*)(kb + (size_t)kr * (3 * D_MODEL) + kc + 16);
            kv3 = *(const s8v*)(kb + (size_t)kr * (3 * D_MODEL) + kc + 24);
            vv0 = *(const s8v*)(vb + (size_t)(2 * kp)      * (3 * D_MODEL) + vd);
            vv1 = *(const s8v*)(vb + (size_t)(2 * kp + 1)  * (3 * D_MODEL) + vd);
            vv2 = *(const s8v*)(vb + (size_t)(2 * kp + 64) * (3 * D_MODEL) + vd);
            vv3 = *(const s8v*)(vb + (size_t)(2 * kp + 65) * (3 * D_MODEL) + vd);
        }
        __syncthreads();

        // S = Q K^T (Q pre-scaled)
        f32x4 sc[8];
        #pragma unroll
        for (int i = 0; i < 8; ++i) sc[i] = zero;
        #pragma unroll
        for (int sub = 0; sub < 2; ++sub) {
            if (sub >= nsub) break;
            #pragma unroll
            for (int kk = 0; kk < 2; ++kk) {
                #pragma unroll
                for (int nt = 0; nt < 4; ++nt) {
                    s8v bv = *(const s8v*)&Ks[sub * 64 + nt * 16 + mm][kk * 32 + q * 8];
                    sc[sub * 4 + nt] = __builtin_amdgcn_mfma_f32_16x16x32_bf16(
                        qf[kk], bv, sc[sub * 4 + nt], 0, 0, 0);
                }
            }
        }

        // p = exp(s); zero masked; pack P (l computed later via ones-MFMA)
        int pswz = 16 * q;
        #pragma unroll
        for (int sub = 0; sub < 2; ++sub) {
            if (sub >= nsub) break;
            bool need_mask = (j0 + sub * 64 + 63) > (q0 + w * 16);
            #pragma unroll
            for (int nt = 0; nt < 4; ++nt) {
                int gj = j0 + sub * 64 + nt * 16 + mm;
                #pragma unroll
                for (int r = 0; r < 4; ++r) {
                    float p = __expf(sc[sub * 4 + nt][r]);
                    if (need_mask && gj > (q0 + w * 16 + q * 4 + r)) p = 0.f;
                    Ps[w * 16 + q * 4 + r][sub * 64 + ((nt * 16 + mm + pswz) & 63)] =
                        (short)f2b_trunc(p);
                }
            }
        }
        // no barrier: each wave reads only its own P rows

        // O += P V ; l += P 1
        int rq16 = 16 * ((mm >> 2) & 3);
        #pragma unroll
        for (int kk4 = 0; kk4 < 4; ++kk4) {
            if (kk4 >= nsub * 2) break;
            int sub = kk4 >> 1, kkl = kk4 & 1;
            s8v av = *(const s8v*)&Ps[w * 16 + mm]
                        [sub * 64 + ((kkl * 32 + q * 8 + rq16) & 63)];
            #pragma unroll
            for (int nt = 0; nt < 4; ++nt) {
                int d = nt * 16 + mm;
                int c = sub * 64 + ((kkl * 32 + q * 8 + (d & 56)) & 63);
                s8v bv = *(const s8v*)&Vts[d][c];
                acc_o[nt] = __builtin_amdgcn_mfma_f32_16x16x32_bf16(av, bv, acc_o[nt], 0, 0, 0);
            }
            acc_l = __builtin_amdgcn_mfma_f32_16x16x32_bf16(av, ones, acc_l, 0, 0, 0);
        }
    }

    // l arrives in C-layout: all 16 cols identical, rows match acc_o rows
    float linv[4];
    #pragma unroll
    for (int r = 0; r < 4; ++r) linv[r] = 1.f / acc_l[r];
    #pragma unroll
    for (int nt = 0; nt < 4; ++nt) {
        int d = nt * 16 + mm;
        #pragma unroll
        for (int r = 0; r < 4; ++r) {
            int row = q0 + w * 16 + q * 4 + r;
            attn_out[(size_t)(b * NSEQ + row) * D_MODEL + h * HSZ + d] =
                f2b(acc_o[nt][r] * linv[r]);
        }
    }
}

// ---------- launch ----------
extern "C" void kernel_launch(void* const* d_in, const int* in_sizes, int n_in,
                              void* d_out, int out_size, void* d_ws, size_t ws_size,
                              hipStream_t stream)
{
    const void* x_raw  = d_in[0];
    const void* ln1s_r = d_in[1];
    const void* ln1b_r = d_in[2];
    const void* wqkv_r = d_in[3];
    const void* wout_r = d_in[4];
    const void* bout_r = d_in[5];
    const void* ln2s_r = d_in[6];
    const void* ln2b_r = d_in[7];
    const void* w1_r   = d_in[8];
    const void* b1_r   = d_in[9];
    const void* w2_r   = d_in[10];
    const void* b2_r   = d_in[11];

    char* ws = (char*)d_ws;
    const size_t MB = 1024 * 1024;
    unsigned short* wt_qkv = (unsigned short*)(ws + 0 * MB);
    unsigned short* wt_out = (unsigned short*)(ws + 6 * MB);
    unsigned short* wt_w1  = (unsigned short*)(ws + 8 * MB);
    unsigned short* wt_w2  = (unsigned short*)(ws + 12 * MB);
    unsigned short* xb     = (unsigned short*)(ws + 16 * MB);
    unsigned short* xn     = (unsigned short*)(ws + 24 * MB);
    unsigned short* qkvb   = (unsigned short*)(ws + 32 * MB);
    unsigned short* x1     = (unsigned short*)(ws + 48 * MB);
    int*            flag   = (int*)           (ws + 56 * MB);
    unsigned short* cbias  = (unsigned short*)(ws + 56 * MB + 1024);
    unsigned short* attnb  = xn;
    unsigned short* xn2    = xn;
    unsigned short* hb     = qkvb;

    unsigned short* c_ln1s = cbias + 0;
    unsigned short* c_ln1b = cbias + 1024;
    unsigned short* c_bout = cbias + 2048;
    unsigned short* c_ln2s = cbias + 3072;
    unsigned short* c_ln2b = cbias + 4096;
    unsigned short* c_b1   = cbias + 5120;
    unsigned short* c_b2   = cbias + 7168;

    sniff_k<<<1, 256, 0, stream>>>((const unsigned short*)x_raw, flag);
    cvt_small_k<<<32, 256, 0, stream>>>(ln1s_r, ln1b_r, bout_r, ln2s_r, ln2b_r,
                                        b1_r, b2_r, cbias, flag);
    transpose_all_k<<<8192, 256, 0, stream>>>(wqkv_r, wout_r, w1_r, w2_r,
                                              wt_qkv, wt_out, wt_w1, wt_w2, flag);
    ln1f_k<<<MROWS, 256, 0, stream>>>(x_raw, c_ln1s, c_ln1b, xb, xn, flag);
    gemm128_k<128, 0, 0, 0><<<dim3(24, 32), 256, 0, stream>>>(
        xn, wt_qkv, nullptr, nullptr, qkvb, MROWS, 3072, 1024, flag);
    fattn_k<<<dim3(NBATCH * NHEAD, NSEQ / 64), 256, 0, stream>>>(qkvb, attnb);
    gemm128_k<64, 0, 1, 0><<<dim3(16, 32), 256, 0, stream>>>(
        attnb, wt_out, c_bout, xb, x1, MROWS, 1024, 1024, flag);
    ln_k<<<MROWS, 256, 0, stream>>>(x1, c_ln2s, c_ln2b, xn2);
    gemm128_k<128, 1, 0, 0><<<dim3(16, 32), 256, 0, stream>>>(
        xn2, wt_w1, c_b1, nullptr, hb, MROWS, 2048, 1024, flag);
    gemm128_k<64, 0, 1, 1><<<dim3(16, 32), 256, 0, stream>>>(
        hb, wt_w2, c_b2, x1, d_out, MROWS, 1024, 2048, flag);
}